// Round 4
// baseline (40014.038 us; speedup 1.0000x reference)
//
#include <hip/hip_runtime.h>
#include <hip/hip_bf16.h>
#include <cmath>

// ---------------- types & helpers ----------------
typedef __attribute__((ext_vector_type(8))) short short8;   // 8 bf16 in 4 VGPRs
typedef __attribute__((ext_vector_type(4))) float f32x4;
typedef __attribute__((ext_vector_type(4))) unsigned int uint32x4;

__device__ inline float bf2f(ushort u) {
    unsigned v = (unsigned)u << 16; float f; __builtin_memcpy(&f, &v, 4); return f;
}
__device__ inline ushort f2bf(float f) {
    __hip_bfloat16 h = __float2bfloat16(f); ushort u; __builtin_memcpy(&u, &h, 2); return u;
}
__device__ inline float sigf(float z) { return 1.f / (1.f + expf(-z)); }

// dims
#define BB 256   // batch
#define LL 256   // seq len
#define HH 512   // hidden = C
#define G4 2048  // 4*H

// ---------------- prologue kernels (unchanged from baseline) ----------------

__global__ __launch_bounds__(256) void init_state(ushort* hp, float* Cst) {
    int i = blockIdx.x * 256 + threadIdx.x;
    hp[i] = 0; Cst[i] = 0.f;
}

__global__ __launch_bounds__(256) void transpose_f32_bf16(
    const float* __restrict__ in, ushort* __restrict__ out, int K, int N)
{
    __shared__ float tile[32][33];
    int tx = threadIdx.x & 31, ty = threadIdx.x >> 5;
    int bk = blockIdx.x * 32, bn = blockIdx.y * 32;
    #pragma unroll
    for (int i = 0; i < 32; i += 8)
        tile[ty + i][tx] = in[(size_t)(bk + ty + i) * N + (bn + tx)];
    __syncthreads();
    #pragma unroll
    for (int i = 0; i < 32; i += 8)
        out[(size_t)(bn + ty + i) * K + (bk + tx)] = f2bf(tile[tx][ty + i]);
}

__global__ __launch_bounds__(256) void combine_w(
    const float* __restrict__ base, const float* __restrict__ A,
    const float* __restrict__ Bm, float* __restrict__ out, int use_base)
{
    int n  = blockIdx.x * 256 + threadIdx.x;
    int k0 = blockIdx.y * 8;
    float acc[8];
    #pragma unroll
    for (int r = 0; r < 8; ++r)
        acc[r] = use_base ? base[(size_t)(k0 + r) * G4 + n] : 0.f;
    for (int m = 0; m < 512; ++m) {
        float bv = Bm[(size_t)m * G4 + n];
        #pragma unroll
        for (int r = 0; r < 8; ++r)
            acc[r] = fmaf(A[(size_t)(k0 + r) * 512 + m], bv, acc[r]);
    }
    #pragma unroll
    for (int r = 0; r < 8; ++r) out[(size_t)(k0 + r) * G4 + n] = acc[r];
}

__global__ __launch_bounds__(256) void bias_g_kernel(
    const float* __restrict__ Wih_b, const float* __restrict__ Whm_b,
    const float* __restrict__ Wmx_b, const float* __restrict__ Wmh_b,
    const float* __restrict__ Whm, float* __restrict__ bias_g)
{
    int n = blockIdx.x * 256 + threadIdx.x;
    float acc = Wih_b[n] + Whm_b[n];
    for (int m = 0; m < 512; ++m)
        acc = fmaf(Wmx_b[m] + Wmh_b[m], Whm[(size_t)m * G4 + n], acc);
    bias_g[n] = acc;
}

// ---------------- fused step kernel ----------------
// Grid: 256 WGs x 256 thr. WG = (rg = blockIdx&15 row-group of 16 batch rows,
// cc = blockIdx>>4 col-chunk of 32 cols). rg's 16 WGs all == rg (mod 8) -> same
// XCD under round-robin dispatch (perf heuristic only; sync is agent-scope).
// Deadlock-free without cooperative launch: 74KB LDS/WG -> >=1 WG/CU capacity,
// 256 WGs <= 256 CUs => all co-resident.

__device__ __forceinline__ void rg_barrier(unsigned int* flag) {
    __threadfence();          // make this WG's global writes device-visible
    __syncthreads();          // all threads' writes+fence done
    if (threadIdx.x == 0) {
        __hip_atomic_fetch_add(flag, 1u, __ATOMIC_ACQ_REL, __HIP_MEMORY_SCOPE_AGENT);
        while (__hip_atomic_load(flag, __ATOMIC_ACQUIRE, __HIP_MEMORY_SCOPE_AGENT) < 16u)
            __builtin_amdgcn_s_sleep(2);
    }
    __syncthreads();
}

// One mogrify stage for this WG's 16x32 tile: out = bf16(2*sig(A @ W) * scale).
// A: bf16 [256][512] global. Wlds: LDS [32 cols][512 K] bf16, XOR-swizzled
// (byte ^= (col&7)<<4). Waves: (ct = wave&1 -> col-tile, kh = wave>>1 -> K half);
// K halves reduced through pbuf.
__device__ __forceinline__ void mog_stage_dev(
    const ushort* __restrict__ A, const ushort* __restrict__ Wlds,
    const ushort* __restrict__ scaleB, const float* __restrict__ scaleF, long sstr,
    ushort* __restrict__ outp, int r0, int c0, int wave, int lane,
    float (*pbuf)[16][16])
{
    int lr = lane & 15, lk = lane >> 4;
    int ct = wave & 1, kh = wave >> 1;
    int colloc = ct * 16 + lr;
    const short8* Ap = (const short8*)(A + (size_t)(r0 + lr) * HH + kh * 256);
    const char* Wb = (const char*)Wlds;
    f32x4 acc = {0.f, 0.f, 0.f, 0.f};
    #pragma unroll
    for (int kk = 0; kk < 8; ++kk) {
        short8 a = Ap[kk * 4 + lk];
        unsigned int byte = ((unsigned)colloc * 1024u +
                             (unsigned)((kh * 256 + kk * 32 + lk * 8) * 2))
                            ^ (((unsigned)colloc & 7u) << 4);
        short8 b = *(const short8*)(Wb + byte);
        acc = __builtin_amdgcn_mfma_f32_16x16x32_bf16(a, b, acc, 0, 0, 0);
    }
    if (kh == 1) {
        #pragma unroll
        for (int r = 0; r < 4; ++r) pbuf[ct][lk * 4 + r][lr] = acc[r];
    }
    __syncthreads();
    if (kh == 0) {
        #pragma unroll
        for (int r = 0; r < 4; ++r) {
            float v = acc[r] + pbuf[ct][lk * 4 + r][lr];
            int row = r0 + lk * 4 + r;        // C/D layout: col=lane&15, row=(lane>>4)*4+r
            int col = c0 + colloc;
            float s = 2.f * sigf(v);
            float sc = scaleF ? scaleF[(size_t)row * sstr + col]
                              : bf2f(scaleB[(size_t)row * HH + col]);
            outp[(size_t)row * HH + col] = f2bf(s * sc);
        }
    }
}

__global__ __launch_bounds__(256) void mog_step(
    const float* __restrict__ x, int t,
    const ushort* __restrict__ QTg, const ushort* __restrict__ RTg,
    const ushort* __restrict__ W1T, const ushort* __restrict__ W2T,
    const float* __restrict__ biasg,
    ushort* __restrict__ xa, ushort* __restrict__ xb,
    ushort* __restrict__ hq, ushort* __restrict__ hr, ushort* __restrict__ hp,
    float* __restrict__ Cst, float* __restrict__ out,
    unsigned int* __restrict__ flags)
{
    __shared__ ushort Qs[32 * 512];          // 32 KB, swizzled [col][K]
    __shared__ ushort Rs[32 * 512];          // 32 KB
    __shared__ float pbuf[2][16][16];        // 2 KB K-half reduce
    __shared__ float gbuf[4][16][32];        // 8 KB gate tiles

    int tid = threadIdx.x;
    int lane = tid & 63, wave = tid >> 6;
    int rg = blockIdx.x & 15, cc = blockIdx.x >> 4;
    int r0 = rg * 16, c0 = cc * 32;

    // Fill Q/R LDS slices (output-cols c0..c0+32, full K), XOR-swizzled.
    // Loaded once per step, reused 3x (Q) / 2x (R).
    {
        const ushort* Qg = QTg + (size_t)c0 * HH;
        const ushort* Rg = RTg + (size_t)c0 * HH;
        #pragma unroll
        for (int i = 0; i < 8; ++i) {
            int ch = i * 256 + tid;              // 0..2047: 32 cols x 64 16B-chunks
            int col = ch >> 6, kc = ch & 63;
            unsigned int byte = ((unsigned)col * 1024u + (unsigned)kc * 16u)
                                ^ (((unsigned)col & 7u) << 4);
            *(uint32x4*)((char*)Qs + byte) = *(const uint32x4*)(Qg + (size_t)col * HH + kc * 8);
            *(uint32x4*)((char*)Rs + byte) = *(const uint32x4*)(Rg + (size_t)col * HH + kc * 8);
        }
    }
    __syncthreads();

    unsigned int* fbase = flags + (size_t)t * 5 * 16 + rg;

    // S1: x1 = 2*sig(h_prev @ Q) * x_t      -> xa   (scale from fp32 input x)
    mog_stage_dev(hp, Qs, nullptr, x + (size_t)t * HH, (long)LL * HH, xa, r0, c0, wave, lane, pbuf);
    rg_barrier(fbase + 0 * 16);
    // S2: h1 = 2*sig(x1 @ R) * h_prev       -> hq
    mog_stage_dev(xa, Rs, hp, nullptr, 0, hq, r0, c0, wave, lane, pbuf);
    rg_barrier(fbase + 1 * 16);
    // S3: x2 = 2*sig(h1 @ Q) * x1           -> xb
    mog_stage_dev(hq, Qs, xa, nullptr, 0, xb, r0, c0, wave, lane, pbuf);
    rg_barrier(fbase + 2 * 16);
    // S4: h2 = 2*sig(x2 @ R) * h1           -> hr
    mog_stage_dev(xb, Rs, hq, nullptr, 0, hr, r0, c0, wave, lane, pbuf);
    rg_barrier(fbase + 3 * 16);
    // S5: x3 = 2*sig(h2 @ Q) * x2           -> xa
    mog_stage_dev(hr, Qs, xb, nullptr, 0, xa, r0, c0, wave, lane, pbuf);
    rg_barrier(fbase + 4 * 16);

    // S6: gates = x3@W1 + h2@W2 + bias; LSTM cell. wave = gate quadrant q.
    // Each wave: 16 rows x 32 cols of gate q (2 col-tiles), K=512 per matrix.
    {
        int lr = lane & 15, lk = lane >> 4;
        int q = wave;
        f32x4 acc0 = {0,0,0,0}, acc1 = {0,0,0,0};
        {
            const short8* Ap = (const short8*)(xa + (size_t)(r0 + lr) * HH);
            const short8* B0 = (const short8*)(W1T + (size_t)(q * 512 + c0 + lr) * HH);
            const short8* B1 = (const short8*)(W1T + (size_t)(q * 512 + c0 + 16 + lr) * HH);
            #pragma unroll
            for (int kk = 0; kk < 16; ++kk) {
                short8 a = Ap[kk * 4 + lk];
                acc0 = __builtin_amdgcn_mfma_f32_16x16x32_bf16(a, B0[kk * 4 + lk], acc0, 0, 0, 0);
                acc1 = __builtin_amdgcn_mfma_f32_16x16x32_bf16(a, B1[kk * 4 + lk], acc1, 0, 0, 0);
            }
        }
        {
            const short8* Ap = (const short8*)(hr + (size_t)(r0 + lr) * HH);
            const short8* B0 = (const short8*)(W2T + (size_t)(q * 512 + c0 + lr) * HH);
            const short8* B1 = (const short8*)(W2T + (size_t)(q * 512 + c0 + 16 + lr) * HH);
            #pragma unroll
            for (int kk = 0; kk < 16; ++kk) {
                short8 a = Ap[kk * 4 + lk];
                acc0 = __builtin_amdgcn_mfma_f32_16x16x32_bf16(a, B0[kk * 4 + lk], acc0, 0, 0, 0);
                acc1 = __builtin_amdgcn_mfma_f32_16x16x32_bf16(a, B1[kk * 4 + lk], acc1, 0, 0, 0);
            }
        }
        float b0 = biasg[q * 512 + c0 + lr];
        float b1 = biasg[q * 512 + c0 + 16 + lr];
        #pragma unroll
        for (int r = 0; r < 4; ++r) {
            gbuf[q][lk * 4 + r][lr]      = acc0[r] + b0;
            gbuf[q][lk * 4 + r][16 + lr] = acc1[r] + b1;
        }
        __syncthreads();
        #pragma unroll
        for (int e = 0; e < 2; ++e) {
            int idx = e * 256 + tid;
            int rl = idx >> 5, cl = idx & 31;
            float ig = sigf(gbuf[0][rl][cl]);
            float fg = sigf(gbuf[1][rl][cl]);
            float cg = tanhf(gbuf[2][rl][cl]);
            float og = sigf(gbuf[3][rl][cl]);
            size_t gi = (size_t)(r0 + rl) * HH + (c0 + cl);
            float C = Cst[gi];
            C = fg * C + ig * cg;
            Cst[gi] = C;
            float h = og * tanhf(C);
            hp[gi] = f2bf(h);
            out[((size_t)(r0 + rl) * LL + t) * HH + (c0 + cl)] = h;
        }
    }
}

// ---------------- host launcher ----------------
extern "C" void kernel_launch(void* const* d_in, const int* in_sizes, int n_in,
                              void* d_out, int out_size, void* d_ws, size_t ws_size,
                              hipStream_t stream)
{
    const float* x     = (const float*)d_in[0];   // (256,256,512)
    const float* Wih_w = (const float*)d_in[1];   // (512,2048)
    const float* Wih_b = (const float*)d_in[2];   // (2048)
    const float* Wmx_w = (const float*)d_in[3];   // (512,512)
    const float* Wmx_b = (const float*)d_in[4];   // (512)
    const float* Wmh_w = (const float*)d_in[5];   // (512,512)
    const float* Wmh_b = (const float*)d_in[6];   // (512)
    const float* Whm_w = (const float*)d_in[7];   // (512,2048)
    const float* Whm_b = (const float*)d_in[8];   // (2048)
    const float* Q     = (const float*)d_in[9];   // (512,512)
    const float* R     = (const float*)d_in[10];  // (512,512)
    float* out = (float*)d_out;                   // (256,256,512)

    char* ws = (char*)d_ws;
    ushort* QT   = (ushort*)ws;               ws += (size_t)512 * 512 * 2;
    ushort* RT   = (ushort*)ws;               ws += (size_t)512 * 512 * 2;
    ushort* W1T  = (ushort*)ws;               ws += (size_t)G4  * 512 * 2;
    ushort* W2T  = (ushort*)ws;               ws += (size_t)G4  * 512 * 2;
    float*  biasg= (float*)ws;                ws += (size_t)G4 * 4;
    ushort* xa   = (ushort*)ws;               ws += (size_t)BB * HH * 2;
    ushort* xb   = (ushort*)ws;               ws += (size_t)BB * HH * 2;
    ushort* hp   = (ushort*)ws;               ws += (size_t)BB * HH * 2;
    ushort* hq   = (ushort*)ws;               ws += (size_t)BB * HH * 2;
    ushort* hr   = (ushort*)ws;               ws += (size_t)BB * HH * 2;
    float*  Cst  = (float*)ws;                ws += (size_t)BB * HH * 4;
    float*  Wtmp = (float*)ws;                ws += (size_t)512 * G4 * 4;   // prologue-only

    // Barrier flags alias the (post-prologue dead) Wtmp region: 256 steps x 5
    // stages x 16 row-groups u32 = 80 KB << 4 MB. Unique slot per (t,s,rg) ->
    // no reset races; re-zeroed every call (graph replays included).
    unsigned int* flags = (unsigned int*)Wtmp;

    // prologue: state init + weight prep
    init_state<<<512, 256, 0, stream>>>(hp, Cst);
    transpose_f32_bf16<<<dim3(16, 16), 256, 0, stream>>>(Q, QT, 512, 512);
    transpose_f32_bf16<<<dim3(16, 16), 256, 0, stream>>>(R, RT, 512, 512);
    combine_w<<<dim3(8, 64), 256, 0, stream>>>(Wih_w, Wmx_w, Whm_w, Wtmp, 1);   // W1 = Wih + Wmx@Whm
    transpose_f32_bf16<<<dim3(16, 64), 256, 0, stream>>>(Wtmp, W1T, 512, G4);
    combine_w<<<dim3(8, 64), 256, 0, stream>>>(nullptr, Wmh_w, Whm_w, Wtmp, 0); // W2 = Wmh@Whm
    transpose_f32_bf16<<<dim3(16, 64), 256, 0, stream>>>(Wtmp, W2T, 512, G4);
    bias_g_kernel<<<8, 256, 0, stream>>>(Wih_b, Whm_b, Wmx_b, Wmh_b, Whm_w, biasg);
    hipMemsetAsync(flags, 0, (size_t)LL * 5 * 16 * sizeof(unsigned int), stream);

    for (int t = 0; t < LL; ++t) {
        mog_step<<<256, 256, 0, stream>>>(x, t, QT, RT, W1T, W2T, biasg,
                                          xa, xb, hq, hr, hp, Cst, out, flags);
    }
}

// Round 5
// 24355.238 us; speedup vs baseline: 1.6429x; 1.6429x over previous
//
#include <hip/hip_runtime.h>
#include <hip/hip_bf16.h>
#include <cmath>

// ---------------- types & helpers ----------------
typedef __attribute__((ext_vector_type(8))) short short8;   // 8 bf16 in 4 VGPRs
typedef __attribute__((ext_vector_type(4))) float f32x4;
typedef __attribute__((ext_vector_type(4))) unsigned int uint32x4;

__device__ inline float bf2f(ushort u) {
    unsigned v = (unsigned)u << 16; float f; __builtin_memcpy(&f, &v, 4); return f;
}
__device__ inline ushort f2bf(float f) {
    __hip_bfloat16 h = __float2bfloat16(f); ushort u; __builtin_memcpy(&u, &h, 2); return u;
}
__device__ inline float sigf(float z) { return 1.f / (1.f + expf(-z)); }

// dims
#define BB 256   // batch
#define LL 256   // seq len
#define HH 512   // hidden = C
#define G4 2048  // 4*H

// ---------------- prologue kernels (unchanged, proven in round 3) ----------------

__global__ __launch_bounds__(256) void init_state(ushort* hp, float* Cst) {
    int i = blockIdx.x * 256 + threadIdx.x;
    hp[i] = 0; Cst[i] = 0.f;
}

__global__ __launch_bounds__(256) void transpose_f32_bf16(
    const float* __restrict__ in, ushort* __restrict__ out, int K, int N)
{
    __shared__ float tile[32][33];
    int tx = threadIdx.x & 31, ty = threadIdx.x >> 5;
    int bk = blockIdx.x * 32, bn = blockIdx.y * 32;
    #pragma unroll
    for (int i = 0; i < 32; i += 8)
        tile[ty + i][tx] = in[(size_t)(bk + ty + i) * N + (bn + tx)];
    __syncthreads();
    #pragma unroll
    for (int i = 0; i < 32; i += 8)
        out[(size_t)(bn + ty + i) * K + (bk + tx)] = f2bf(tile[tx][ty + i]);
}

__global__ __launch_bounds__(256) void combine_w(
    const float* __restrict__ base, const float* __restrict__ A,
    const float* __restrict__ Bm, float* __restrict__ out, int use_base)
{
    int n  = blockIdx.x * 256 + threadIdx.x;
    int k0 = blockIdx.y * 8;
    float acc[8];
    #pragma unroll
    for (int r = 0; r < 8; ++r)
        acc[r] = use_base ? base[(size_t)(k0 + r) * G4 + n] : 0.f;
    for (int m = 0; m < 512; ++m) {
        float bv = Bm[(size_t)m * G4 + n];
        #pragma unroll
        for (int r = 0; r < 8; ++r)
            acc[r] = fmaf(A[(size_t)(k0 + r) * 512 + m], bv, acc[r]);
    }
    #pragma unroll
    for (int r = 0; r < 8; ++r) out[(size_t)(k0 + r) * G4 + n] = acc[r];
}

__global__ __launch_bounds__(256) void bias_g_kernel(
    const float* __restrict__ Wih_b, const float* __restrict__ Whm_b,
    const float* __restrict__ Wmx_b, const float* __restrict__ Wmh_b,
    const float* __restrict__ Whm, float* __restrict__ bias_g)
{
    int n = blockIdx.x * 256 + threadIdx.x;
    float acc = Wih_b[n] + Whm_b[n];
    for (int m = 0; m < 512; ++m)
        acc = fmaf(Wmx_b[m] + Wmh_b[m], Whm[(size_t)m * G4 + n], acc);
    bias_g[n] = acc;
}

// ---------------- K1: all five mogrify stages, row-local ----------------
// Grid: 16 WGs x 1024 thr (16 waves). WG owns batch rows r0..r0+16 and ALL 512
// cols -> zero inter-WG communication (rows are independent; weights read-only).
// Activations live in LDS: Xl/Hl [16 rows][512] bf16, XOR-swizzled
// (byte ^= (row&7)<<4) to kill the 16-way bank conflict of 1KB row stride.
// Each wave owns 32 output cols per stage; weights stream from L2 (QT/RT,
// [out-col][K] rows) straight into MFMA B-frags. 6 __syncthreads total.

__device__ __forceinline__ unsigned swz(unsigned row, unsigned byteInRow) {
    return (row * 1024u + byteInRow) ^ ((row & 7u) << 4);
}

__global__ __launch_bounds__(1024) void mog5(
    const float* __restrict__ x, int t,
    const ushort* __restrict__ QT, const ushort* __restrict__ RT,
    const ushort* __restrict__ hp,
    ushort* __restrict__ x3g, ushort* __restrict__ h2g)
{
    __shared__ ushort Xl[16 * 512];   // 16 KB
    __shared__ ushort Hl[16 * 512];   // 16 KB

    int tid = threadIdx.x;
    int lane = tid & 63, wave = tid >> 6;       // wave 0..15
    int r0 = blockIdx.x * 16;
    int lr = lane & 15, lk = lane >> 4;         // lk = K-subgroup 0..3
    int wc = wave * 32;                         // this wave's col base

    // ---- fill Hl = h_prev (swizzled); 1024 thr = 16 rows x 64 x 16B ----
    {
        int row = tid >> 6, kc = tid & 63;
        *(uint32x4*)((char*)Hl + swz(row, kc * 16u)) =
            *(const uint32x4*)(hp + (size_t)(r0 + row) * HH + kc * 8);
    }
    __syncthreads();

    // stage macro: OUT[row][wave cols] = bf16( 2*sig(A_lds @ W) * scale )
    // A-frag: lane lr = A row, lk = k-subgroup; B-frag: lane lr = W out-col row.
    // C/D layout (verified round 0/3): col = lane&15, row = (lane>>4)*4 + r.
#define MOG_STAGE(Alds, Wg, Olds, SCALE_EXPR)                                   \
    {                                                                           \
        f32x4 acc0 = {0,0,0,0}, acc1 = {0,0,0,0};                               \
        const short8* B0 = (const short8*)(Wg + (size_t)(wc + lr) * HH);        \
        const short8* B1 = (const short8*)(Wg + (size_t)(wc + 16 + lr) * HH);   \
        _Pragma("unroll")                                                       \
        for (int kk = 0; kk < 16; ++kk) {                                       \
            short8 a = *(const short8*)((char*)Alds +                           \
                          swz((unsigned)lr, (unsigned)((kk * 32 + lk * 8) * 2)));\
            acc0 = __builtin_amdgcn_mfma_f32_16x16x32_bf16(a, B0[kk*4+lk], acc0, 0,0,0); \
            acc1 = __builtin_amdgcn_mfma_f32_16x16x32_bf16(a, B1[kk*4+lk], acc1, 0,0,0); \
        }                                                                       \
        _Pragma("unroll")                                                       \
        for (int r = 0; r < 4; ++r) {                                           \
            int row = lk * 4 + r;                                               \
            {                                                                   \
                int col = wc + lr;                                              \
                float v = acc0[r];                                              \
                float sc = (SCALE_EXPR);                                        \
                *(ushort*)((char*)Olds + swz((unsigned)row, (unsigned)(col*2))) \
                    = f2bf(2.f * sigf(v) * sc);                                 \
            }                                                                   \
            {                                                                   \
                int col = wc + 16 + lr;                                         \
                float v = acc1[r];                                              \
                float sc = (SCALE_EXPR);                                        \
                *(ushort*)((char*)Olds + swz((unsigned)row, (unsigned)(col*2))) \
                    = f2bf(2.f * sigf(v) * sc);                                 \
            }                                                                   \
        }                                                                       \
    }

    // S1: x1 = 2*sig(h0 @ Q) * x_t   (scale from fp32 input x, layout (B,L,C))
    MOG_STAGE(Hl, QT, Xl,
              x[((size_t)(r0 + row) * LL + t) * HH + col]);
    __syncthreads();
    // S2: h1 = 2*sig(x1 @ R) * h0    (scale = current Hl value, in-place)
    MOG_STAGE(Xl, RT, Hl,
              bf2f(*(const ushort*)((char*)Hl + swz((unsigned)row, (unsigned)(col*2)))));
    __syncthreads();
    // S3: x2 = 2*sig(h1 @ Q) * x1
    MOG_STAGE(Hl, QT, Xl,
              bf2f(*(const ushort*)((char*)Xl + swz((unsigned)row, (unsigned)(col*2)))));
    __syncthreads();
    // S4: h2 = 2*sig(x2 @ R) * h1
    MOG_STAGE(Xl, RT, Hl,
              bf2f(*(const ushort*)((char*)Hl + swz((unsigned)row, (unsigned)(col*2)))));
    __syncthreads();
    // S5: x3 = 2*sig(h2 @ Q) * x2
    MOG_STAGE(Hl, QT, Xl,
              bf2f(*(const ushort*)((char*)Xl + swz((unsigned)row, (unsigned)(col*2)))));
    __syncthreads();
#undef MOG_STAGE

    // ---- write x3, h2 to global (de-swizzle), 16B per thread each ----
    {
        int row = tid >> 6, kc = tid & 63;
        *(uint32x4*)(x3g + (size_t)(r0 + row) * HH + kc * 8) =
            *(const uint32x4*)((char*)Xl + swz(row, kc * 16u));
        *(uint32x4*)(h2g + (size_t)(r0 + row) * HH + kc * 8) =
            *(const uint32x4*)((char*)Hl + swz(row, kc * 16u));
    }
}

// ---------------- K2: gates + LSTM cell (unchanged from passing round-3) ----------------
__global__ __launch_bounds__(256) void gates_lstm(
    const ushort* __restrict__ X3, const ushort* __restrict__ H2,
    const ushort* __restrict__ W1T, const ushort* __restrict__ W2T,
    const float* __restrict__ biasg, float* __restrict__ Cst,
    ushort* __restrict__ Hb, float* __restrict__ outF, long out_stride)
{
    __shared__ float gq[4][32][32];
    int lane = threadIdx.x & 63;
    int q = threadIdx.x >> 6;           // wave index = gate quadrant (i,f,g,o)
    int r0 = blockIdx.x * 32;
    int c0 = blockIdx.y * 32;
    int lr = lane & 15, lk = lane >> 4;

    f32x4 a00 = {0,0,0,0}, a01 = {0,0,0,0}, a10 = {0,0,0,0}, a11 = {0,0,0,0};

    {   // X3 @ W1T
        const short8* A0 = (const short8*)(X3 + (size_t)(r0 + lr) * HH);
        const short8* A1 = (const short8*)(X3 + (size_t)(r0 + 16 + lr) * HH);
        const short8* B0 = (const short8*)(W1T + (size_t)(q * 512 + c0 + lr) * HH);
        const short8* B1 = (const short8*)(W1T + (size_t)(q * 512 + c0 + 16 + lr) * HH);
        #pragma unroll
        for (int kk = 0; kk < 16; ++kk) {
            short8 x0 = A0[kk * 4 + lk], x1 = A1[kk * 4 + lk];
            short8 w0 = B0[kk * 4 + lk], w1 = B1[kk * 4 + lk];
            a00 = __builtin_amdgcn_mfma_f32_16x16x32_bf16(x0, w0, a00, 0, 0, 0);
            a01 = __builtin_amdgcn_mfma_f32_16x16x32_bf16(x0, w1, a01, 0, 0, 0);
            a10 = __builtin_amdgcn_mfma_f32_16x16x32_bf16(x1, w0, a10, 0, 0, 0);
            a11 = __builtin_amdgcn_mfma_f32_16x16x32_bf16(x1, w1, a11, 0, 0, 0);
        }
    }
    {   // + H2 @ W2T
        const short8* A0 = (const short8*)(H2 + (size_t)(r0 + lr) * HH);
        const short8* A1 = (const short8*)(H2 + (size_t)(r0 + 16 + lr) * HH);
        const short8* B0 = (const short8*)(W2T + (size_t)(q * 512 + c0 + lr) * HH);
        const short8* B1 = (const short8*)(W2T + (size_t)(q * 512 + c0 + 16 + lr) * HH);
        #pragma unroll
        for (int kk = 0; kk < 16; ++kk) {
            short8 x0 = A0[kk * 4 + lk], x1 = A1[kk * 4 + lk];
            short8 w0 = B0[kk * 4 + lk], w1 = B1[kk * 4 + lk];
            a00 = __builtin_amdgcn_mfma_f32_16x16x32_bf16(x0, w0, a00, 0, 0, 0);
            a01 = __builtin_amdgcn_mfma_f32_16x16x32_bf16(x0, w1, a01, 0, 0, 0);
            a10 = __builtin_amdgcn_mfma_f32_16x16x32_bf16(x1, w0, a10, 0, 0, 0);
            a11 = __builtin_amdgcn_mfma_f32_16x16x32_bf16(x1, w1, a11, 0, 0, 0);
        }
    }

    #pragma unroll
    for (int r = 0; r < 4; ++r) {
        gq[q][lk * 4 + r     ][lr     ] = a00[r] + biasg[q * 512 + c0 + lr];
        gq[q][lk * 4 + r     ][lr + 16] = a01[r] + biasg[q * 512 + c0 + lr + 16];
        gq[q][lk * 4 + r + 16][lr     ] = a10[r] + biasg[q * 512 + c0 + lr];
        gq[q][lk * 4 + r + 16][lr + 16] = a11[r] + biasg[q * 512 + c0 + lr + 16];
    }
    __syncthreads();

    #pragma unroll
    for (int e = 0; e < 4; ++e) {
        int idx = e * 256 + threadIdx.x;
        int rl = idx >> 5, cl = idx & 31;
        float ig = sigf(gq[0][rl][cl]);
        float fg = sigf(gq[1][rl][cl]);
        float cg = tanhf(gq[2][rl][cl]);
        float og = sigf(gq[3][rl][cl]);
        size_t gi = (size_t)(r0 + rl) * HH + (c0 + cl);
        float C = Cst[gi];
        C = fg * C + ig * cg;
        Cst[gi] = C;
        float h = og * tanhf(C);
        Hb[gi] = f2bf(h);
        outF[(size_t)(r0 + rl) * out_stride + (c0 + cl)] = h;
    }
}

// ---------------- host launcher ----------------
extern "C" void kernel_launch(void* const* d_in, const int* in_sizes, int n_in,
                              void* d_out, int out_size, void* d_ws, size_t ws_size,
                              hipStream_t stream)
{
    const float* x     = (const float*)d_in[0];   // (256,256,512)
    const float* Wih_w = (const float*)d_in[1];   // (512,2048)
    const float* Wih_b = (const float*)d_in[2];   // (2048)
    const float* Wmx_w = (const float*)d_in[3];   // (512,512)
    const float* Wmx_b = (const float*)d_in[4];   // (512)
    const float* Wmh_w = (const float*)d_in[5];   // (512,512)
    const float* Wmh_b = (const float*)d_in[6];   // (512)
    const float* Whm_w = (const float*)d_in[7];   // (512,2048)
    const float* Whm_b = (const float*)d_in[8];   // (2048)
    const float* Q     = (const float*)d_in[9];   // (512,512)
    const float* R     = (const float*)d_in[10];  // (512,512)
    float* out = (float*)d_out;                   // (256,256,512)

    char* ws = (char*)d_ws;
    ushort* QT   = (ushort*)ws;               ws += (size_t)512 * 512 * 2;      // bf16 [outcol][K]
    ushort* RT   = (ushort*)ws;               ws += (size_t)512 * 512 * 2;
    ushort* W1T  = (ushort*)ws;               ws += (size_t)G4  * 512 * 2;
    ushort* W2T  = (ushort*)ws;               ws += (size_t)G4  * 512 * 2;
    float*  biasg= (float*)ws;                ws += (size_t)G4 * 4;
    ushort* x3g  = (ushort*)ws;               ws += (size_t)BB * HH * 2;
    ushort* h2g  = (ushort*)ws;               ws += (size_t)BB * HH * 2;
    ushort* hp   = (ushort*)ws;               ws += (size_t)BB * HH * 2;
    float*  Cst  = (float*)ws;                ws += (size_t)BB * HH * 4;
    float*  Wtmp = (float*)ws;                ws += (size_t)512 * G4 * 4;       // prologue-only

    // prologue: state init + weight prep
    init_state<<<512, 256, 0, stream>>>(hp, Cst);
    transpose_f32_bf16<<<dim3(16, 16), 256, 0, stream>>>(Q, QT, 512, 512);
    transpose_f32_bf16<<<dim3(16, 16), 256, 0, stream>>>(R, RT, 512, 512);
    combine_w<<<dim3(8, 64), 256, 0, stream>>>(Wih_w, Wmx_w, Whm_w, Wtmp, 1);   // W1 = Wih + Wmx@Whm
    transpose_f32_bf16<<<dim3(16, 64), 256, 0, stream>>>(Wtmp, W1T, 512, G4);
    combine_w<<<dim3(8, 64), 256, 0, stream>>>(nullptr, Wmh_w, Whm_w, Wtmp, 0); // W2 = Wmh@Whm
    transpose_f32_bf16<<<dim3(16, 64), 256, 0, stream>>>(Wtmp, W2T, 512, G4);
    bias_g_kernel<<<8, 256, 0, stream>>>(Wih_b, Whm_b, Wmx_b, Wmh_b, Whm_w, biasg);

    const long xstride = (long)LL * HH;   // 131072
    for (int t = 0; t < LL; ++t) {
        // K1: all 5 mogrify stages, row-local (16 WGs x 1024 thr)
        mog5<<<16, 1024, 0, stream>>>(x, t, QT, RT, hp, x3g, h2g);
        // K2: gates + LSTM cell (col-split, 128 WGs)
        gates_lstm<<<dim3(8, 16), 256, 0, stream>>>(x3g, h2g, W1T, W2T, biasg, Cst, hp,
                                                    out + (size_t)t * HH, xstride);
    }
}

// Round 6
// 9166.386 us; speedup vs baseline: 4.3653x; 2.6570x over previous
//
#include <hip/hip_runtime.h>
#include <hip/hip_bf16.h>
#include <cmath>

// ---------------- types & helpers ----------------
typedef __attribute__((ext_vector_type(8))) short short8;   // 8 bf16
typedef __attribute__((ext_vector_type(4))) float f32x4;
typedef __attribute__((ext_vector_type(2))) float f32x2;
typedef __attribute__((ext_vector_type(4))) unsigned int uint32x4;

union AF { unsigned long long q[2]; short8 s; };

__device__ inline float bf2f(ushort u) {
    unsigned v = (unsigned)u << 16; float f; __builtin_memcpy(&f, &v, 4); return f;
}
__device__ inline ushort f2bf(float f) {
    __hip_bfloat16 h = __float2bfloat16(f); ushort u; __builtin_memcpy(&u, &h, 2); return u;
}
__device__ inline float sigf(float z) { return 1.f / (1.f + expf(-z)); }

// system-scope (fabric-coherent, cache-bypass) data movement — no cache-wide fences
__device__ __forceinline__ unsigned long long sysld64(const void* p) {
    return __hip_atomic_load((unsigned long long*)p, __ATOMIC_RELAXED, __HIP_MEMORY_SCOPE_SYSTEM);
}
__device__ __forceinline__ void sysst32(void* p, unsigned v) {
    __hip_atomic_store((unsigned*)p, v, __ATOMIC_RELAXED, __HIP_MEMORY_SCOPE_SYSTEM);
}

// dims
#define BB 256
#define LL 256
#define HH 512
#define G4 2048

// XOR swizzle for 1024-B LDS rows (kills the row-stride bank alias; proven r4/r5)
__device__ __forceinline__ unsigned swz(unsigned row, unsigned byteInRow) {
    return (row * 1024u + byteInRow) ^ ((row & 7u) << 4);
}

// ---------------- prologue kernels (proven rounds 3/5) ----------------

__global__ __launch_bounds__(256) void init_state(ushort* hp) {
    int i = blockIdx.x * 256 + threadIdx.x;
    hp[i] = 0;
}

__global__ __launch_bounds__(256) void transpose_f32_bf16(
    const float* __restrict__ in, ushort* __restrict__ out, int K, int N)
{
    __shared__ float tile[32][33];
    int tx = threadIdx.x & 31, ty = threadIdx.x >> 5;
    int bk = blockIdx.x * 32, bn = blockIdx.y * 32;
    #pragma unroll
    for (int i = 0; i < 32; i += 8)
        tile[ty + i][tx] = in[(size_t)(bk + ty + i) * N + (bn + tx)];
    __syncthreads();
    #pragma unroll
    for (int i = 0; i < 32; i += 8)
        out[(size_t)(bn + ty + i) * K + (bk + tx)] = f2bf(tile[tx][ty + i]);
}

__global__ __launch_bounds__(256) void combine_w(
    const float* __restrict__ base, const float* __restrict__ A,
    const float* __restrict__ Bm, float* __restrict__ out, int use_base)
{
    int n  = blockIdx.x * 256 + threadIdx.x;
    int k0 = blockIdx.y * 8;
    float acc[8];
    #pragma unroll
    for (int r = 0; r < 8; ++r)
        acc[r] = use_base ? base[(size_t)(k0 + r) * G4 + n] : 0.f;
    for (int m = 0; m < 512; ++m) {
        float bv = Bm[(size_t)m * G4 + n];
        #pragma unroll
        for (int r = 0; r < 8; ++r)
            acc[r] = fmaf(A[(size_t)(k0 + r) * 512 + m], bv, acc[r]);
    }
    #pragma unroll
    for (int r = 0; r < 8; ++r) out[(size_t)(k0 + r) * G4 + n] = acc[r];
}

__global__ __launch_bounds__(256) void bias_g_kernel(
    const float* __restrict__ Wih_b, const float* __restrict__ Whm_b,
    const float* __restrict__ Wmx_b, const float* __restrict__ Wmh_b,
    const float* __restrict__ Whm, float* __restrict__ bias_g)
{
    int n = blockIdx.x * 256 + threadIdx.x;
    float acc = Wih_b[n] + Whm_b[n];
    for (int m = 0; m < 512; ++m)
        acc = fmaf(Wmx_b[m] + Wmh_b[m], Whm[(size_t)m * G4 + n], acc);
    bias_g[n] = acc;
}

// ---------------- persistent fused kernel ----------------
// 256 WGs x 256 thr; WG = (rb = blockIdx>>4: 16 batch rows, cs = blockIdx&15:
// 32 cols). 1 WG/CU (LDS-forced). Row-group rb = 16 CONSECUTIVE blockIdx ->
// partial-machine progress group-by-group (no cooperative launch needed).
// Sync: per-(rb,t,stage) flag, agent-scope atomic RMW arrive+poll (coherent
// across XCDs, no cache invalidates). Data across WGs: system-scope relaxed
// atomics (sc0 sc1 bypass) -> weights stay L2-cached, never invalidated.

__device__ __forceinline__ void rb_barrier(unsigned* flag) {
    asm volatile("s_waitcnt vmcnt(0)" ::: "memory");   // my sc1 stores done
    __syncthreads();                                   // all waves done
    if (threadIdx.x == 0) {
        __hip_atomic_fetch_add(flag, 1u, __ATOMIC_RELAXED, __HIP_MEMORY_SCOPE_AGENT);
        while (__hip_atomic_fetch_add(flag, 0u, __ATOMIC_RELAXED, __HIP_MEMORY_SCOPE_AGENT) < 16u)
            __builtin_amdgcn_s_sleep(2);
    }
    __syncthreads();
}

// One mogrify stage for this WG's 16 rows x 32 cols:
//   val = 2*sig( (A @ W)[row][col] ) * scale;  myBuf & outG <- bf16(val)
// A: global bf16 [256][512] read sc1 (written by siblings last stage).
// Wlds: LDS [32 local cols][512 K] swizzled. Waves: ct=wave&1 col-tile,
// kh=wave>>1 K-half; halves reduced via pbuf. scale: x input (S1) or myBuf.
__device__ __forceinline__ void mog_stage_p(
    const ushort* __restrict__ Ag, const ushort* Wlds,
    ushort (*myBuf)[32], ushort* __restrict__ outG,
    const float* __restrict__ xscale, float (*pbuf)[16][16],
    int r0, int cs, int t, int tid)
{
    int lane = tid & 63, wave = tid >> 6;
    int lr = lane & 15, lk = lane >> 4;
    int ct = wave & 1, kh = wave >> 1;
    int colloc = ct * 16 + lr;

    float xs[4];
    if (xscale != nullptr && kh == 0) {
        #pragma unroll
        for (int r = 0; r < 4; ++r)
            xs[r] = xscale[((size_t)(r0 + lk * 4 + r) * LL + t) * HH + cs * 32 + colloc];
    }

    const char* Ab = (const char*)(Ag + (size_t)(r0 + lr) * HH) + kh * 512 + lk * 16;
    f32x4 acc = {0.f, 0.f, 0.f, 0.f};
    #pragma unroll
    for (int kk = 0; kk < 8; ++kk) {
        AF af;
        af.q[0] = sysld64(Ab + kk * 64);
        af.q[1] = sysld64(Ab + kk * 64 + 8);
        short8 b = *(const short8*)((const char*)Wlds +
                     swz((unsigned)colloc, (unsigned)(kh * 512 + kk * 64 + lk * 16)));
        acc = __builtin_amdgcn_mfma_f32_16x16x32_bf16(af.s, b, acc, 0, 0, 0);
    }
    if (kh == 1) {
        #pragma unroll
        for (int r = 0; r < 4; ++r) pbuf[ct][lk * 4 + r][lr] = acc[r];
    }
    __syncthreads();
    if (kh == 0) {
        #pragma unroll
        for (int r = 0; r < 4; ++r) {
            float v = acc[r] + pbuf[ct][lk * 4 + r][lr];
            float sc = (xscale != nullptr) ? xs[r] : bf2f(myBuf[lk * 4 + r][colloc]);
            myBuf[lk * 4 + r][colloc] = f2bf(2.f * sigf(v) * sc);   // C/D: col=lane&15, row=(lane>>4)*4+r
        }
    }
    __syncthreads();
    {   // publish my 1 KB tile (coalesced u32 sc1 stores, 1/thread)
        int row = tid >> 4, c2 = tid & 15;
        unsigned v = *(const unsigned*)&myBuf[row][c2 * 2];
        sysst32((char*)outG + (((size_t)(r0 + row)) * HH + cs * 32 + c2 * 2) * 2, v);
    }
}

__global__ __launch_bounds__(256) void moglstm_persistent(
    const float* __restrict__ x,
    const ushort* __restrict__ QT, const ushort* __restrict__ RT,
    const ushort* __restrict__ W1T, const ushort* __restrict__ W2T,
    const float* __restrict__ biasg,
    ushort* __restrict__ hp, ushort* __restrict__ xa, ushort* __restrict__ hb1,
    ushort* __restrict__ xb, ushort* __restrict__ hb2, ushort* __restrict__ xc,
    float* __restrict__ out, unsigned* __restrict__ flags)
{
    __shared__ ushort QTs[32 * 512];      // 32 KB swizzled [local col][K]
    __shared__ ushort RTs[32 * 512];      // 32 KB
    __shared__ float  pbuf[2][16][16];    // 2 KB
    __shared__ ushort myX[16][32];        // 1 KB  (my cols' latest x)
    __shared__ ushort myH[16][32];        // 1 KB  (my cols' latest h)
    __shared__ float  gbuf[4][16][32];    // 8 KB
    __shared__ ushort padl[3072];         // pad -> 82 KB total -> 1 WG/CU

    int tid = threadIdx.x;
    asm volatile("" :: "v"((unsigned)(size_t)&padl[0]));   // keep padl allocated

    int rb = blockIdx.x >> 4, cs = blockIdx.x & 15;
    int r0 = rb * 16;
    int lane = tid & 63, wave = tid >> 6;
    int lr = lane & 15, lk = lane >> 4;

    // Q/R weight slices -> LDS once for the whole sequence (normal cached loads)
    #pragma unroll
    for (int i = 0; i < 8; ++i) {
        int ch = i * 256 + tid, col = ch >> 6, kc = ch & 63;
        *(uint32x4*)((char*)QTs + swz((unsigned)col, (unsigned)(kc * 16))) =
            *(const uint32x4*)(QT + (size_t)(cs * 32 + col) * HH + kc * 8);
        *(uint32x4*)((char*)RTs + swz((unsigned)col, (unsigned)(kc * 16))) =
            *(const uint32x4*)(RT + (size_t)(cs * 32 + col) * HH + kc * 8);
    }
    ((unsigned*)myH)[tid] = 0;            // h0 = 0 (16*32 ushort = 256 u32)
    float Creg0 = 0.f, Creg1 = 0.f;       // cell state lives in VGPRs all run
    __syncthreads();

    unsigned* fb = flags + (size_t)rb * (LL * 6);

    for (int t = 0; t < LL; ++t) {
        unsigned* ft = fb + t * 6;
        // S1: x1 = 2*sig(h0 @ Q) * x_t
        mog_stage_p(hp,  QTs, myX, xa,  x,       pbuf, r0, cs, t, tid); rb_barrier(ft + 0);
        // S2: h1 = 2*sig(x1 @ R) * h0
        mog_stage_p(xa,  RTs, myH, hb1, nullptr, pbuf, r0, cs, t, tid); rb_barrier(ft + 1);
        // S3: x2 = 2*sig(h1 @ Q) * x1
        mog_stage_p(hb1, QTs, myX, xb,  nullptr, pbuf, r0, cs, t, tid); rb_barrier(ft + 2);
        // S4: h2 = 2*sig(x2 @ R) * h1
        mog_stage_p(xb,  RTs, myH, hb2, nullptr, pbuf, r0, cs, t, tid); rb_barrier(ft + 3);
        // S5: x3 = 2*sig(h2 @ Q) * x2
        mog_stage_p(hb2, QTs, myX, xc,  nullptr, pbuf, r0, cs, t, tid); rb_barrier(ft + 4);

        // S6: gates = x3@W1 + h2@W2 + bias; LSTM cell. wave = gate quadrant.
        {
            int q = wave;
            f32x4 acc0 = {0,0,0,0}, acc1 = {0,0,0,0};
            {   // x3 @ W1 (A sc1; B normal cached from L2)
                const char* Ab = (const char*)(xc + (size_t)(r0 + lr) * HH) + lk * 16;
                const short8* B0 = (const short8*)(W1T + (size_t)(q * 512 + cs * 32 + lr) * HH);
                const short8* B1 = (const short8*)(W1T + (size_t)(q * 512 + cs * 32 + 16 + lr) * HH);
                #pragma unroll
                for (int kk = 0; kk < 16; ++kk) {
                    AF af; af.q[0] = sysld64(Ab + kk * 64); af.q[1] = sysld64(Ab + kk * 64 + 8);
                    acc0 = __builtin_amdgcn_mfma_f32_16x16x32_bf16(af.s, B0[kk * 4 + lk], acc0, 0, 0, 0);
                    acc1 = __builtin_amdgcn_mfma_f32_16x16x32_bf16(af.s, B1[kk * 4 + lk], acc1, 0, 0, 0);
                }
            }
            {   // + h2 @ W2
                const char* Ab = (const char*)(hb2 + (size_t)(r0 + lr) * HH) + lk * 16;
                const short8* B0 = (const short8*)(W2T + (size_t)(q * 512 + cs * 32 + lr) * HH);
                const short8* B1 = (const short8*)(W2T + (size_t)(q * 512 + cs * 32 + 16 + lr) * HH);
                #pragma unroll
                for (int kk = 0; kk < 16; ++kk) {
                    AF af; af.q[0] = sysld64(Ab + kk * 64); af.q[1] = sysld64(Ab + kk * 64 + 8);
                    acc0 = __builtin_amdgcn_mfma_f32_16x16x32_bf16(af.s, B0[kk * 4 + lk], acc0, 0, 0, 0);
                    acc1 = __builtin_amdgcn_mfma_f32_16x16x32_bf16(af.s, B1[kk * 4 + lk], acc1, 0, 0, 0);
                }
            }
            float b0 = biasg[q * 512 + cs * 32 + lr];
            float b1 = biasg[q * 512 + cs * 32 + 16 + lr];
            #pragma unroll
            for (int r = 0; r < 4; ++r) {
                gbuf[q][lk * 4 + r][lr]      = acc0[r] + b0;
                gbuf[q][lk * 4 + r][16 + lr] = acc1[r] + b1;
            }
            __syncthreads();
            {   // cell: thread owns (row = tid>>4, cols 2*(tid&15)+{0,1}) forever
                int row = tid >> 4, c2 = tid & 15;
                int colg = cs * 32 + c2 * 2;
                float i0 = sigf(gbuf[0][row][c2 * 2]),     f0 = sigf(gbuf[1][row][c2 * 2]);
                float g0 = tanhf(gbuf[2][row][c2 * 2]),    o0 = sigf(gbuf[3][row][c2 * 2]);
                Creg0 = f0 * Creg0 + i0 * g0;
                float h0v = o0 * tanhf(Creg0);
                float i1 = sigf(gbuf[0][row][c2 * 2 + 1]), f1 = sigf(gbuf[1][row][c2 * 2 + 1]);
                float g1 = tanhf(gbuf[2][row][c2 * 2 + 1]), o1 = sigf(gbuf[3][row][c2 * 2 + 1]);
                Creg1 = f1 * Creg1 + i1 * g1;
                float h1v = o1 * tanhf(Creg1);
                f32x2 hv2 = {h0v, h1v};
                *(f32x2*)(out + ((size_t)(r0 + row) * LL + t) * HH + colg) = hv2;  // output (B,L,H)
                unsigned hu = (unsigned)f2bf(h0v) | ((unsigned)f2bf(h1v) << 16);
                sysst32((char*)hp + (((size_t)(r0 + row)) * HH + colg) * 2, hu);   // h_t for S1(t+1)
                *(unsigned*)&myH[row][c2 * 2] = hu;                                // local copy for S2
            }
            rb_barrier(ft + 5);
        }
    }
}

// ---------------- host launcher ----------------
extern "C" void kernel_launch(void* const* d_in, const int* in_sizes, int n_in,
                              void* d_out, int out_size, void* d_ws, size_t ws_size,
                              hipStream_t stream)
{
    const float* x     = (const float*)d_in[0];   // (256,256,512)
    const float* Wih_w = (const float*)d_in[1];   // (512,2048)
    const float* Wih_b = (const float*)d_in[2];   // (2048)
    const float* Wmx_w = (const float*)d_in[3];   // (512,512)
    const float* Wmx_b = (const float*)d_in[4];   // (512)
    const float* Wmh_w = (const float*)d_in[5];   // (512,512)
    const float* Wmh_b = (const float*)d_in[6];   // (512)
    const float* Whm_w = (const float*)d_in[7];   // (512,2048)
    const float* Whm_b = (const float*)d_in[8];   // (2048)
    const float* Q     = (const float*)d_in[9];   // (512,512)
    const float* R     = (const float*)d_in[10];  // (512,512)
    float* out = (float*)d_out;                   // (256,256,512)

    char* ws = (char*)d_ws;
    ushort* QT   = (ushort*)ws;               ws += (size_t)512 * 512 * 2;   // bf16 [outcol][K]
    ushort* RT   = (ushort*)ws;               ws += (size_t)512 * 512 * 2;
    ushort* W1T  = (ushort*)ws;               ws += (size_t)G4  * 512 * 2;
    ushort* W2T  = (ushort*)ws;               ws += (size_t)G4  * 512 * 2;
    float*  biasg= (float*)ws;                ws += (size_t)G4 * 4;
    ushort* xa   = (ushort*)ws;               ws += (size_t)BB * HH * 2;
    ushort* hb1  = (ushort*)ws;               ws += (size_t)BB * HH * 2;
    ushort* xb   = (ushort*)ws;               ws += (size_t)BB * HH * 2;
    ushort* hb2  = (ushort*)ws;               ws += (size_t)BB * HH * 2;
    ushort* xc   = (ushort*)ws;               ws += (size_t)BB * HH * 2;
    ushort* hp   = (ushort*)ws;               ws += (size_t)BB * HH * 2;
    float*  Wtmp = (float*)ws;                ws += (size_t)512 * G4 * 4;    // prologue-only

    // Barrier flags alias post-prologue-dead Wtmp: 16 rb x 256 t x 6 stages u32
    // = 96 KB. Unique slot per (rb,t,stage); re-zeroed every call/replay.
    unsigned* flags = (unsigned*)Wtmp;

    // prologue: state init + weight prep
    init_state<<<512, 256, 0, stream>>>(hp);
    transpose_f32_bf16<<<dim3(16, 16), 256, 0, stream>>>(Q, QT, 512, 512);
    transpose_f32_bf16<<<dim3(16, 16), 256, 0, stream>>>(R, RT, 512, 512);
    combine_w<<<dim3(8, 64), 256, 0, stream>>>(Wih_w, Wmx_w, Whm_w, Wtmp, 1);   // W1 = Wih + Wmx@Whm
    transpose_f32_bf16<<<dim3(16, 64), 256, 0, stream>>>(Wtmp, W1T, 512, G4);
    combine_w<<<dim3(8, 64), 256, 0, stream>>>(nullptr, Wmh_w, Whm_w, Wtmp, 0); // W2 = Wmh@Whm
    transpose_f32_bf16<<<dim3(16, 64), 256, 0, stream>>>(Wtmp, W2T, 512, G4);
    bias_g_kernel<<<8, 256, 0, stream>>>(Wih_b, Whm_b, Wmx_b, Wmh_b, Whm_w, biasg);
    hipMemsetAsync(flags, 0, (size_t)16 * LL * 6 * sizeof(unsigned), stream);

    // one persistent kernel for the entire sequence
    moglstm_persistent<<<256, 256, 0, stream>>>(x, QT, RT, W1T, W2T, biasg,
                                                hp, xa, hb1, xb, hb2, xc, out, flags);
}

// Round 8
// 8732.870 us; speedup vs baseline: 4.5820x; 1.0496x over previous
//
#include <hip/hip_runtime.h>
#include <hip/hip_bf16.h>
#include <cmath>

// ---------------- types & helpers ----------------
typedef __attribute__((ext_vector_type(8))) short short8;   // 8 bf16
typedef __attribute__((ext_vector_type(4))) float f32x4;
typedef __attribute__((ext_vector_type(2))) float f32x2;
typedef __attribute__((ext_vector_type(4))) unsigned int u32x4;

union AFu { u32x4 v; short8 s; };

__device__ inline float bf2f(ushort u) {
    unsigned v = (unsigned)u << 16; float f; __builtin_memcpy(&f, &v, 4); return f;
}
__device__ inline ushort f2bf(float f) {
    __hip_bfloat16 h = __float2bfloat16(f); ushort u; __builtin_memcpy(&u, &h, 2); return u;
}
__device__ inline float sigf(float z) { return 1.f / (1.f + expf(-z)); }

// system-scope (fabric-coherent, cache-bypass) data movement — proven r6
__device__ __forceinline__ void sysst32(void* p, unsigned v) {
    __hip_atomic_store((unsigned*)p, v, __ATOMIC_RELAXED, __HIP_MEMORY_SCOPE_SYSTEM);
}

// 8 x 16B system-scope loads at base + {0,64,...,448}, ONE wait (batched to
// amortize fabric latency; r6 issued these as 16 separate atomic loads).
__device__ __forceinline__ void ld8_sys(const void* base,
    u32x4& a0, u32x4& a1, u32x4& a2, u32x4& a3,
    u32x4& a4, u32x4& a5, u32x4& a6, u32x4& a7)
{
    asm volatile(
        "global_load_dwordx4 %0, %8, off sc0 sc1\n\t"
        "global_load_dwordx4 %1, %8, off offset:64 sc0 sc1\n\t"
        "global_load_dwordx4 %2, %8, off offset:128 sc0 sc1\n\t"
        "global_load_dwordx4 %3, %8, off offset:192 sc0 sc1\n\t"
        "global_load_dwordx4 %4, %8, off offset:256 sc0 sc1\n\t"
        "global_load_dwordx4 %5, %8, off offset:320 sc0 sc1\n\t"
        "global_load_dwordx4 %6, %8, off offset:384 sc0 sc1\n\t"
        "global_load_dwordx4 %7, %8, off offset:448 sc0 sc1\n\t"
        "s_waitcnt vmcnt(0)"
        : "=&v"(a0), "=&v"(a1), "=&v"(a2), "=&v"(a3),
          "=&v"(a4), "=&v"(a5), "=&v"(a6), "=&v"(a7)
        : "v"(base)
        : "memory");
}

// dims
#define BB 256
#define LL 256
#define HH 512
#define G4 2048

// XOR swizzle for 1024-B LDS rows (kills row-stride bank alias; proven r4-r6)
__device__ __forceinline__ unsigned swz(unsigned row, unsigned byteInRow) {
    return (row * 1024u + byteInRow) ^ ((row & 7u) << 4);
}

// Row-group barrier, epoch-slot scheme — ZERO RMWs. Each WG stores epoch to
// its own slot (agent-scope relaxed atomic store); threads 0-15 poll the 16
// slots with agent-scope relaxed atomic LOADS. Monotonic epochs -> no reset.
// Per-wave vmcnt(0) BEFORE __syncthreads drains every wave's data stores.
__device__ __forceinline__ void rb_barrier(unsigned* slots, int sub, unsigned epoch) {
    asm volatile("s_waitcnt vmcnt(0)" ::: "memory");
    __syncthreads();
    if (threadIdx.x == 0)
        __hip_atomic_store(slots + sub, epoch, __ATOMIC_RELAXED, __HIP_MEMORY_SCOPE_AGENT);
    if (threadIdx.x < 16)
        while (__hip_atomic_load(slots + threadIdx.x, __ATOMIC_RELAXED,
                                 __HIP_MEMORY_SCOPE_AGENT) < epoch)
            __builtin_amdgcn_s_sleep(1);
    __syncthreads();
}

// ---------------- prologue kernels (proven rounds 3-6) ----------------

__global__ __launch_bounds__(256) void init_state(ushort* hp) {
    int i = blockIdx.x * 256 + threadIdx.x;
    hp[i] = 0;
}

__global__ __launch_bounds__(256) void transpose_f32_bf16(
    const float* __restrict__ in, ushort* __restrict__ out, int K, int N)
{
    __shared__ float tile[32][33];
    int tx = threadIdx.x & 31, ty = threadIdx.x >> 5;
    int bk = blockIdx.x * 32, bn = blockIdx.y * 32;
    #pragma unroll
    for (int i = 0; i < 32; i += 8)
        tile[ty + i][tx] = in[(size_t)(bk + ty + i) * N + (bn + tx)];
    __syncthreads();
    #pragma unroll
    for (int i = 0; i < 32; i += 8)
        out[(size_t)(bn + ty + i) * K + (bk + tx)] = f2bf(tile[tx][ty + i]);
}

__global__ __launch_bounds__(256) void combine_w(
    const float* __restrict__ base, const float* __restrict__ A,
    const float* __restrict__ Bm, float* __restrict__ out, int use_base)
{
    int n  = blockIdx.x * 256 + threadIdx.x;
    int k0 = blockIdx.y * 8;
    float acc[8];
    #pragma unroll
    for (int r = 0; r < 8; ++r)
        acc[r] = use_base ? base[(size_t)(k0 + r) * G4 + n] : 0.f;
    for (int m = 0; m < 512; ++m) {
        float bv = Bm[(size_t)m * G4 + n];
        #pragma unroll
        for (int r = 0; r < 8; ++r)
            acc[r] = fmaf(A[(size_t)(k0 + r) * 512 + m], bv, acc[r]);
    }
    #pragma unroll
    for (int r = 0; r < 8; ++r) out[(size_t)(k0 + r) * G4 + n] = acc[r];
}

__global__ __launch_bounds__(256) void bias_g_kernel(
    const float* __restrict__ Wih_b, const float* __restrict__ Whm_b,
    const float* __restrict__ Wmx_b, const float* __restrict__ Wmh_b,
    const float* __restrict__ Whm, float* __restrict__ bias_g)
{
    int n = blockIdx.x * 256 + threadIdx.x;
    float acc = Wih_b[n] + Whm_b[n];
    for (int m = 0; m < 512; ++m)
        acc = fmaf(Wmx_b[m] + Wmh_b[m], Whm[(size_t)m * G4 + n], acc);
    bias_g[n] = acc;
}

// ---------------- persistent fused kernel ----------------
// 256 WGs x 256 thr, 1 WG/CU (82KB LDS forces it; co-residency proven r6).
// WG = (rb = blockIdx>>4: 16 batch rows, cs = blockIdx&15: 32 cols).
// Data across WGs: system-scope relaxed (cache-bypass, proven r6).
// Sync: epoch-slot barrier above (no RMWs anywhere).

__device__ __forceinline__ void mog_stage_p(
    const ushort* __restrict__ Ag, const ushort* Wlds,
    ushort (*myBuf)[32], ushort* __restrict__ outG,
    const float* __restrict__ xscale, float (*pbuf)[16][16],
    int r0, int cs, int t, int tid)
{
    int lane = tid & 63, wave = tid >> 6;
    int lr = lane & 15, lk = lane >> 4;
    int ct = wave & 1, kh = wave >> 1;
    int colloc = ct * 16 + lr;

    float xs[4];
    if (xscale != nullptr && kh == 0) {
        #pragma unroll
        for (int r = 0; r < 4; ++r)
            xs[r] = xscale[((size_t)(r0 + lk * 4 + r) * LL + t) * HH + cs * 32 + colloc];
    }

    const char* Ab = (const char*)(Ag + (size_t)(r0 + lr) * HH) + kh * 512 + lk * 16;
    u32x4 a0, a1, a2, a3, a4, a5, a6, a7;
    ld8_sys(Ab, a0, a1, a2, a3, a4, a5, a6, a7);

    f32x4 acc = {0.f, 0.f, 0.f, 0.f};
#define MOGMF(i, ai) { AFu u; u.v = ai;                                          \
        short8 bfr = *(const short8*)((const char*)Wlds +                        \
            swz((unsigned)colloc, (unsigned)(kh * 512 + i * 64 + lk * 16)));     \
        acc = __builtin_amdgcn_mfma_f32_16x16x32_bf16(u.s, bfr, acc, 0, 0, 0); }
    MOGMF(0, a0) MOGMF(1, a1) MOGMF(2, a2) MOGMF(3, a3)
    MOGMF(4, a4) MOGMF(5, a5) MOGMF(6, a6) MOGMF(7, a7)
#undef MOGMF

    if (kh == 1) {
        #pragma unroll
        for (int r = 0; r < 4; ++r) pbuf[ct][lk * 4 + r][lr] = acc[r];
    }
    __syncthreads();
    if (kh == 0) {
        #pragma unroll
        for (int r = 0; r < 4; ++r) {
            float v = acc[r] + pbuf[ct][lk * 4 + r][lr];
            float sc = (xscale != nullptr) ? xs[r] : bf2f(myBuf[lk * 4 + r][colloc]);
            myBuf[lk * 4 + r][colloc] = f2bf(2.f * sigf(v) * sc);  // C/D: col=lane&15, row=(lane>>4)*4+r
        }
    }
    __syncthreads();
    {   // publish my 1 KB tile (coalesced u32 system stores, 1/thread)
        int row = tid >> 4, c2 = tid & 15;
        unsigned v = *(const unsigned*)&myBuf[row][c2 * 2];
        sysst32((char*)outG + (((size_t)(r0 + row)) * HH + cs * 32 + c2 * 2) * 2, v);
    }
}

__global__ __launch_bounds__(256) void moglstm_persistent(
    const float* __restrict__ x,
    const ushort* __restrict__ QT, const ushort* __restrict__ RT,
    const ushort* __restrict__ W1T, const ushort* __restrict__ W2T,
    const float* __restrict__ biasg,
    ushort* __restrict__ hp, ushort* __restrict__ xa, ushort* __restrict__ hb1,
    ushort* __restrict__ xb, ushort* __restrict__ hb2, ushort* __restrict__ xc,
    float* __restrict__ out, unsigned* __restrict__ flags)
{
    __shared__ ushort QTs[32 * 512];      // 32 KB swizzled [local col][K]
    __shared__ ushort RTs[32 * 512];      // 32 KB
    __shared__ float  pbuf[2][16][16];    // 2 KB
    __shared__ ushort myX[16][32];        // 1 KB
    __shared__ ushort myH[16][32];        // 1 KB
    __shared__ float  gbuf[4][16][32];    // 8 KB
    __shared__ ushort padl[3072];         // pad -> 82 KB -> exactly 1 WG/CU

    int tid = threadIdx.x;
    asm volatile("" :: "v"((unsigned)(size_t)&padl[0]));   // keep padl allocated

    int rb = blockIdx.x >> 4, cs = blockIdx.x & 15;
    int r0 = rb * 16;
    int lane = tid & 63, wave = tid >> 6;
    int lr = lane & 15, lk = lane >> 4;

    // Q/R weight slices -> LDS once (plain cached loads; read-only)
    #pragma unroll
    for (int i = 0; i < 8; ++i) {
        int ch = i * 256 + tid, col = ch >> 6, kc = ch & 63;
        *(u32x4*)((char*)QTs + swz((unsigned)col, (unsigned)(kc * 16))) =
            *(const u32x4*)(QT + (size_t)(cs * 32 + col) * HH + kc * 8);
        *(u32x4*)((char*)RTs + swz((unsigned)col, (unsigned)(kc * 16))) =
            *(const u32x4*)(RT + (size_t)(cs * 32 + col) * HH + kc * 8);
    }
    ((unsigned*)myH)[tid] = 0;            // h0 = 0
    float Creg0 = 0.f, Creg1 = 0.f;       // cell state lives in VGPRs all run
    __syncthreads();

    unsigned* slots = flags + rb * 16;    // 16 u32 = one line per row-group

    for (int t = 0; t < LL; ++t) {
        unsigned ep = (unsigned)t * 6u;
        // S1: x1 = 2*sig(h0 @ Q) * x_t
        mog_stage_p(hp,  QTs, myX, xa,  x,       pbuf, r0, cs, t, tid); rb_barrier(slots, cs, ep + 1);
        // S2: h1 = 2*sig(x1 @ R) * h0
        mog_stage_p(xa,  RTs, myH, hb1, nullptr, pbuf, r0, cs, t, tid); rb_barrier(slots, cs, ep + 2);
        // S3: x2 = 2*sig(h1 @ Q) * x1
        mog_stage_p(hb1, QTs, myX, xb,  nullptr, pbuf, r0, cs, t, tid); rb_barrier(slots, cs, ep + 3);
        // S4: h2 = 2*sig(x2 @ R) * h1
        mog_stage_p(xb,  RTs, myH, hb2, nullptr, pbuf, r0, cs, t, tid); rb_barrier(slots, cs, ep + 4);
        // S5: x3 = 2*sig(h2 @ Q) * x2
        mog_stage_p(hb2, QTs, myX, xc,  nullptr, pbuf, r0, cs, t, tid); rb_barrier(slots, cs, ep + 5);

        // S6: gates = x3@W1 + h2@W2 + bias; LSTM cell. wave = gate quadrant.
        {
            int q = wave;
            f32x4 acc0 = {0,0,0,0}, acc1 = {0,0,0,0};
            u32x4 a0, a1, a2, a3, a4, a5, a6, a7;
#define GATEMF(ai, Bp, accv) { AFu u; u.v = ai;                                   \
            accv = __builtin_amdgcn_mfma_f32_16x16x32_bf16(u.s, Bp, accv, 0,0,0); }
            {   // x3 @ W1 (A system-scope; B plain cached)
                const char* Ab = (const char*)(xc + (size_t)(r0 + lr) * HH) + lk * 16;
                const short8* B0 = (const short8*)(W1T + (size_t)(q * 512 + cs * 32 + lr) * HH);
                const short8* B1 = (const short8*)(W1T + (size_t)(q * 512 + cs * 32 + 16 + lr) * HH);
                ld8_sys(Ab, a0, a1, a2, a3, a4, a5, a6, a7);
                GATEMF(a0, B0[0*4+lk], acc0) GATEMF(a0, B1[0*4+lk], acc1)
                GATEMF(a1, B0[1*4+lk], acc0) GATEMF(a1, B1[1*4+lk], acc1)
                GATEMF(a2, B0[2*4+lk], acc0) GATEMF(a2, B1[2*4+lk], acc1)
                GATEMF(a3, B0[3*4+lk], acc0) GATEMF(a3, B1[3*4+lk], acc1)
                GATEMF(a4, B0[4*4+lk], acc0) GATEMF(a4, B1[4*4+lk], acc1)
                GATEMF(a5, B0[5*4+lk], acc0) GATEMF(a5, B1[5*4+lk], acc1)
                GATEMF(a6, B0[6*4+lk], acc0) GATEMF(a6, B1[6*4+lk], acc1)
                GATEMF(a7, B0[7*4+lk], acc0) GATEMF(a7, B1[7*4+lk], acc1)
                ld8_sys(Ab + 512, a0, a1, a2, a3, a4, a5, a6, a7);
                GATEMF(a0, B0[8*4+lk],  acc0) GATEMF(a0, B1[8*4+lk],  acc1)
                GATEMF(a1, B0[9*4+lk],  acc0) GATEMF(a1, B1[9*4+lk],  acc1)
                GATEMF(a2, B0[10*4+lk], acc0) GATEMF(a2, B1[10*4+lk], acc1)
                GATEMF(a3, B0[11*4+lk], acc0) GATEMF(a3, B1[11*4+lk], acc1)
                GATEMF(a4, B0[12*4+lk], acc0) GATEMF(a4, B1[12*4+lk], acc1)
                GATEMF(a5, B0[13*4+lk], acc0) GATEMF(a5, B1[13*4+lk], acc1)
                GATEMF(a6, B0[14*4+lk], acc0) GATEMF(a6, B1[14*4+lk], acc1)
                GATEMF(a7, B0[15*4+lk], acc0) GATEMF(a7, B1[15*4+lk], acc1)
            }
            {   // + h2 @ W2
                const char* Ab = (const char*)(hb2 + (size_t)(r0 + lr) * HH) + lk * 16;
                const short8* B0 = (const short8*)(W2T + (size_t)(q * 512 + cs * 32 + lr) * HH);
                const short8* B1 = (const short8*)(W2T + (size_t)(q * 512 + cs * 32 + 16 + lr) * HH);
                ld8_sys(Ab, a0, a1, a2, a3, a4, a5, a6, a7);
                GATEMF(a0, B0[0*4+lk], acc0) GATEMF(a0, B1[0*4+lk], acc1)
                GATEMF(a1, B0[1*4+lk], acc0) GATEMF(a1, B1[1*4+lk], acc1)
                GATEMF(a2, B0[2*4+lk], acc0) GATEMF(a2, B1[2*4+lk], acc1)
                GATEMF(a3, B0[3*4+lk], acc0) GATEMF(a3, B1[3*4+lk], acc1)
                GATEMF(a4, B0[4*4+lk], acc0) GATEMF(a4, B1[4*4+lk], acc1)
                GATEMF(a5, B0[5*4+lk], acc0) GATEMF(a5, B1[5*4+lk], acc1)
                GATEMF(a6, B0[6*4+lk], acc0) GATEMF(a6, B1[6*4+lk], acc1)
                GATEMF(a7, B0[7*4+lk], acc0) GATEMF(a7, B1[7*4+lk], acc1)
                ld8_sys(Ab + 512, a0, a1, a2, a3, a4, a5, a6, a7);
                GATEMF(a0, B0[8*4+lk],  acc0) GATEMF(a0, B1[8*4+lk],  acc1)
                GATEMF(a1, B0[9*4+lk],  acc0) GATEMF(a1, B1[9*4+lk],  acc1)
                GATEMF(a2, B0[10*4+lk], acc0) GATEMF(a2, B1[10*4+lk], acc1)
                GATEMF(a3, B0[11*4+lk], acc0) GATEMF(a3, B1[11*4+lk], acc1)
                GATEMF(a4, B0[12*4+lk], acc0) GATEMF(a4, B1[12*4+lk], acc1)
                GATEMF(a5, B0[13*4+lk], acc0) GATEMF(a5, B1[13*4+lk], acc1)
                GATEMF(a6, B0[14*4+lk], acc0) GATEMF(a6, B1[14*4+lk], acc1)
                GATEMF(a7, B0[15*4+lk], acc0) GATEMF(a7, B1[15*4+lk], acc1)
            }
#undef GATEMF
            float b0 = biasg[q * 512 + cs * 32 + lr];
            float b1 = biasg[q * 512 + cs * 32 + 16 + lr];
            #pragma unroll
            for (int r = 0; r < 4; ++r) {
                gbuf[q][lk * 4 + r][lr]      = acc0[r] + b0;
                gbuf[q][lk * 4 + r][16 + lr] = acc1[r] + b1;
            }
            __syncthreads();
            {   // cell: thread owns (row=tid>>4, cols 2*(tid&15)+{0,1}) forever
                int row = tid >> 4, c2 = tid & 15;
                int colg = cs * 32 + c2 * 2;
                float i0 = sigf(gbuf[0][row][c2 * 2]),      f0 = sigf(gbuf[1][row][c2 * 2]);
                float g0 = tanhf(gbuf[2][row][c2 * 2]),     o0 = sigf(gbuf[3][row][c2 * 2]);
                Creg0 = f0 * Creg0 + i0 * g0;
                float h0v = o0 * tanhf(Creg0);
                float i1 = sigf(gbuf[0][row][c2 * 2 + 1]),  f1 = sigf(gbuf[1][row][c2 * 2 + 1]);
                float g1 = tanhf(gbuf[2][row][c2 * 2 + 1]), o1 = sigf(gbuf[3][row][c2 * 2 + 1]);
                Creg1 = f1 * Creg1 + i1 * g1;
                float h1v = o1 * tanhf(Creg1);
                f32x2 hv2 = {h0v, h1v};
                *(f32x2*)(out + ((size_t)(r0 + row) * LL + t) * HH + colg) = hv2;  // (B,L,H)
                unsigned hu = (unsigned)f2bf(h0v) | ((unsigned)f2bf(h1v) << 16);
                sysst32((char*)hp + (((size_t)(r0 + row)) * HH + colg) * 2, hu);   // h_t for S1(t+1)
                *(unsigned*)&myH[row][c2 * 2] = hu;                                // local copy for S2
            }
            rb_barrier(slots, cs, ep + 6);
        }
    }
}

// ---------------- host launcher ----------------
extern "C" void kernel_launch(void* const* d_in, const int* in_sizes, int n_in,
                              void* d_out, int out_size, void* d_ws, size_t ws_size,
                              hipStream_t stream)
{
    const float* x     = (const float*)d_in[0];   // (256,256,512)
    const float* Wih_w = (const float*)d_in[1];   // (512,2048)
    const float* Wih_b = (const float*)d_in[2];   // (2048)
    const float* Wmx_w = (const float*)d_in[3];   // (512,512)
    const float* Wmx_b = (const float*)d_in[4];   // (512)
    const float* Wmh_w = (const float*)d_in[5];   // (512,512)
    const float* Wmh_b = (const float*)d_in[6];   // (512)
    const float* Whm_w = (const float*)d_in[7];   // (512,2048)
    const float* Whm_b = (const float*)d_in[8];   // (2048)
    const float* Q     = (const float*)d_in[9];   // (512,512)
    const float* R     = (const float*)d_in[10];  // (512,512)
    float* out = (float*)d_out;                   // (256,256,512)

    char* ws = (char*)d_ws;
    ushort* QT   = (ushort*)ws;               ws += (size_t)512 * 512 * 2;   // bf16 [outcol][K]
    ushort* RT   = (ushort*)ws;               ws += (size_t)512 * 512 * 2;
    ushort* W1T  = (ushort*)ws;               ws += (size_t)G4  * 512 * 2;
    ushort* W2T  = (ushort*)ws;               ws += (size_t)G4  * 512 * 2;
    float*  biasg= (float*)ws;                ws += (size_t)G4 * 4;
    ushort* xa   = (ushort*)ws;               ws += (size_t)BB * HH * 2;
    ushort* hb1  = (ushort*)ws;               ws += (size_t)BB * HH * 2;
    ushort* xb   = (ushort*)ws;               ws += (size_t)BB * HH * 2;
    ushort* hb2  = (ushort*)ws;               ws += (size_t)BB * HH * 2;
    ushort* xc   = (ushort*)ws;               ws += (size_t)BB * HH * 2;
    ushort* hp   = (ushort*)ws;               ws += (size_t)BB * HH * 2;
    float*  Wtmp = (float*)ws;                ws += (size_t)512 * G4 * 4;    // prologue-only

    // Epoch slots alias post-prologue-dead Wtmp: 16 rb x 16 slots u32 = 1 KB.
    // Monotonic epochs -> zeroed once per call (graph replays re-run memset).
    unsigned* flags = (unsigned*)Wtmp;

    // prologue: state init + weight prep
    init_state<<<512, 256, 0, stream>>>(hp);
    transpose_f32_bf16<<<dim3(16, 16), 256, 0, stream>>>(Q, QT, 512, 512);
    transpose_f32_bf16<<<dim3(16, 16), 256, 0, stream>>>(R, RT, 512, 512);
    combine_w<<<dim3(8, 64), 256, 0, stream>>>(Wih_w, Wmx_w, Whm_w, Wtmp, 1);   // W1 = Wih + Wmx@Whm
    transpose_f32_bf16<<<dim3(16, 64), 256, 0, stream>>>(Wtmp, W1T, 512, G4);
    combine_w<<<dim3(8, 64), 256, 0, stream>>>(nullptr, Wmh_w, Whm_w, Wtmp, 0); // W2 = Wmh@Whm
    transpose_f32_bf16<<<dim3(16, 64), 256, 0, stream>>>(Wtmp, W2T, 512, G4);
    bias_g_kernel<<<8, 256, 0, stream>>>(Wih_b, Whm_b, Wmx_b, Wmh_b, Whm_w, biasg);
    hipMemsetAsync(flags, 0, (size_t)16 * 16 * sizeof(unsigned), stream);

    // one persistent kernel for the entire sequence
    moglstm_persistent<<<256, 256, 0, stream>>>(x, QT, RT, W1T, W2T, biasg,
                                                hp, xa, hb1, xb, hb2, xc, out, flags);
}